// Round 1
// 1676.447 us; speedup vs baseline: 1.1818x; 1.1818x over previous
//
#include <hip/hip_runtime.h>

#define NN 50000
#define EE 1600000
// IN=128, HID=32, OUT=64, ED=64, H=4, HC=128

__device__ inline float b2f(unsigned short u) {
    return __uint_as_float(((unsigned)u) << 16);
}
__device__ inline unsigned short f2bf(float f) {
    unsigned u = __float_as_uint(f);
    unsigned r = 0x7fffu + ((u >> 16) & 1u);
    return (unsigned short)((u + r) >> 16);
}
__device__ inline void stv(float* p, size_t i, float v) { p[i] = v; }
__device__ inline void stv(unsigned short* p, size_t i, float v) { p[i] = f2bf(v); }

// ---------------- dtype sniffer: is input f32 (1) or bf16 (0)? ----------------
__global__ void sniff_kernel(const void* w, int* flags) {
    int lane = threadIdx.x;
    const unsigned short* u = (const unsigned short*)w;
    int bad = 0;
    for (int i = lane; i < 256; i += 64) {
        float f = b2f(u[i]);
        if (!(fabsf(f) < 2.0f)) bad++;  // catches big values AND NaN
    }
    unsigned long long m = __ballot(bad > 0);
    if (lane == 0) {
        flags[0] = (__popcll(m) > 8) ? 1 : 0;  // 1 = inputs are f32
        flags[1] = 0;                          // constant "bf16" flag
    }
}

// ---------------- canonicalize all weights/biases to bf16 in ws ----------------
struct WTab {
    const void* p[18];
    int off[18];
    int sz[18];
};
__global__ void __launch_bounds__(256) convert_kernel(WTab t, const int* __restrict__ flags,
                                                      unsigned short* __restrict__ dst) {
    int f32 = flags[0];
    int ti = blockIdx.y;
    int i = blockIdx.x * 256 + threadIdx.x;
    if (i < t.sz[ti]) {
        dst[t.off[ti] + i] = f32 ? f2bf(((const float*)t.p[ti])[i])
                                 : ((const unsigned short*)t.p[ti])[i];
    }
}

// ---------------- CSR build ----------------
__global__ void __launch_bounds__(256) count_kernel(const int* __restrict__ dst,
                                                    int* __restrict__ cnt) {
    int e = blockIdx.x * 256 + threadIdx.x;
    if (e < EE) atomicAdd(&cnt[dst[e]], 1);
}

__global__ void __launch_bounds__(1024) scan_kernel(int* __restrict__ cntfill,
                                                    int* __restrict__ rowptr) {
    __shared__ int s[1024];
    __shared__ int carry_s;
    int tid = threadIdx.x;
    if (tid == 0) carry_s = 0;
    __syncthreads();
    for (int base = 0; base < NN; base += 4096) {
        int i0 = base + tid * 4;
        int v0 = (i0 + 0 < NN) ? cntfill[i0 + 0] : 0;
        int v1 = (i0 + 1 < NN) ? cntfill[i0 + 1] : 0;
        int v2 = (i0 + 2 < NN) ? cntfill[i0 + 2] : 0;
        int v3 = (i0 + 3 < NN) ? cntfill[i0 + 3] : 0;
        int tsum = v0 + v1 + v2 + v3;
        s[tid] = tsum;
        __syncthreads();
        for (int off = 1; off < 1024; off <<= 1) {
            int t = (tid >= off) ? s[tid - off] : 0;
            __syncthreads();
            s[tid] += t;
            __syncthreads();
        }
        int carry = carry_s;
        int excl = carry + s[tid] - tsum;
        int e0 = excl, e1 = excl + v0, e2 = e1 + v1, e3 = e2 + v2;
        if (i0 + 0 < NN) { rowptr[i0 + 0] = e0; cntfill[i0 + 0] = e0; }
        if (i0 + 1 < NN) { rowptr[i0 + 1] = e1; cntfill[i0 + 1] = e1; }
        if (i0 + 2 < NN) { rowptr[i0 + 2] = e2; cntfill[i0 + 2] = e2; }
        if (i0 + 3 < NN) { rowptr[i0 + 3] = e3; cntfill[i0 + 3] = e3; }
        __syncthreads();
        if (tid == 1023) carry_s = carry + s[1023];
        __syncthreads();
    }
    if (tid == 0) rowptr[NN] = carry_s;
}

__global__ void __launch_bounds__(256) fill_kernel(const int* __restrict__ dst,
                                                   int* __restrict__ cntfill,
                                                   int* __restrict__ perm) {
    int e = blockIdx.x * 256 + threadIdx.x;
    if (e < EE) {
        int p = atomicAdd(&cntfill[dst[e]], 1);
        perm[p] = e;
    }
}

// ---------------- node GEMM: C[nrows,OD] = X[nrows,K] @ W[K,OD] + b ----------------
// stores at C[rr*ldc + c*cstride + coff] so k/v can be interleaved into one kv buffer
template <typename TO, int K, int OD, int TR>
__global__ void __launch_bounds__(256) gemm_node(const void* __restrict__ X,
                                                 const int* __restrict__ flagp,
                                                 const unsigned short* __restrict__ W,
                                                 const unsigned short* __restrict__ bias,
                                                 TO* __restrict__ C, int nrows,
                                                 int ldc, int cstride, int coff) {
    constexpr int TRP = TR + 4;
    __shared__ unsigned short Ws[K * OD];
    __shared__ float Xs[K * TRP];
    int tid = threadIdx.x;
    int xf32 = *flagp;
    for (int i = tid; i < K * OD; i += 256) Ws[i] = W[i];
    int row0 = blockIdx.x * TR;
    const float* Xf = (const float*)X;
    const unsigned short* Xu = (const unsigned short*)X;
    for (int i = tid; i < TR * K; i += 256) {
        int r = i / K, kk = i % K;
        int rr = row0 + r;
        float vv = 0.f;
        if (rr < nrows) {
            size_t idx = (size_t)rr * K + kk;
            vv = xf32 ? Xf[idx] : b2f(Xu[idx]);
        }
        Xs[kk * TRP + r] = vv;
    }
    __syncthreads();
    constexpr int CG = OD / 4;
    int rg = tid / CG, cg = tid % CG;
    int r0 = rg * 4, c0 = cg * 4;
    float acc[4][4] = {};
#pragma unroll 4
    for (int kk = 0; kk < K; ++kk) {
        const float4 xv = *(const float4*)&Xs[kk * TRP + r0];
        ushort4 wu = *(const ushort4*)&Ws[kk * OD + c0];
        float xa[4] = {xv.x, xv.y, xv.z, xv.w};
        float wb[4] = {b2f(wu.x), b2f(wu.y), b2f(wu.z), b2f(wu.w)};
#pragma unroll
        for (int i2 = 0; i2 < 4; i2++)
#pragma unroll
            for (int j2 = 0; j2 < 4; j2++) acc[i2][j2] += xa[i2] * wb[j2];
    }
    float bb[4];
#pragma unroll
    for (int j2 = 0; j2 < 4; j2++) bb[j2] = b2f(bias[c0 + j2]);
#pragma unroll
    for (int i2 = 0; i2 < 4; i2++) {
        int rr = row0 + r0 + i2;
        if (rr < nrows) {
#pragma unroll
            for (int j2 = 0; j2 < 4; j2++)
                stv(C, (size_t)rr * ldc + (size_t)(c0 + j2) * cstride + coff,
                    acc[i2][j2] + bb[j2]);
        }
    }
}

// ---------------- qe1[n, h*64+d] = sum_c q1[n,h*32+c] * We1[d, h*32+c] ----------------
__global__ void __launch_bounds__(256) qe1_kernel(const unsigned short* __restrict__ q,
                                                  const unsigned short* __restrict__ We,
                                                  float* __restrict__ qe) {
    __shared__ float Ws[64 * 129];
    __shared__ float qs[8 * 128];
    int tid = threadIdx.x;
    for (int i = tid; i < 64 * 128; i += 256) Ws[(i / 128) * 129 + (i % 128)] = b2f(We[i]);
    int n0 = blockIdx.x * 8;
    for (int i = tid; i < 8 * 128; i += 256) {
        int n = n0 + (i >> 7);
        qs[i] = (n < NN) ? b2f(q[(size_t)n * 128 + (i & 127)]) : 0.f;
    }
    __syncthreads();
    int h = tid >> 6, d = tid & 63;
    for (int nl = 0; nl < 8; ++nl) {
        int n = n0 + nl;
        if (n < NN) {
            float acc = 0.f;
#pragma unroll
            for (int c = 0; c < 32; ++c)
                acc += qs[nl * 128 + h * 32 + c] * Ws[d * 129 + h * 32 + c];
            qe[(size_t)n * 256 + h * 64 + d] = acc;
        }
    }
}

// ---------------- qe2[n,d] = sum_c q2[n,c] * We2[d,c] ----------------
__global__ void __launch_bounds__(256) qe2_kernel(const unsigned short* __restrict__ q,
                                                  const unsigned short* __restrict__ We,
                                                  float* __restrict__ qe) {
    __shared__ float Ws[64 * 65];
    __shared__ float qs[4 * 64];
    int tid = threadIdx.x;
    for (int i = tid; i < 64 * 64; i += 256) Ws[(i / 64) * 65 + (i % 64)] = b2f(We[i]);
    int n0 = blockIdx.x * 4;
    {
        int n = n0 + (tid >> 6);
        qs[tid] = (n < NN) ? b2f(q[(size_t)n * 64 + (tid & 63)]) : 0.f;
    }
    __syncthreads();
    int nl = tid >> 6, d = tid & 63;
    int n = n0 + nl;
    if (n < NN) {
        float acc = 0.f;
#pragma unroll
        for (int c = 0; c < 64; ++c) acc += qs[nl * 64 + c] * Ws[d * 65 + c];
        qe[(size_t)n * 64 + d] = acc;
    }
}

// ---------------- layer1 per-node flash pass: one wave per dst node ----------------
// kv layout: kv[n][128][2] ushort (k,v interleaved). lane owns channels c1,c2 and
// ef/qe dims d in {4dq..4dq+3} (contiguous -> float4 loads). 4-edge unrolled with
// joint online-softmax update + next-group index prefetch for MLP.
__global__ void __launch_bounds__(256) node_pass1(
    const int* __restrict__ rowptr, const int* __restrict__ perm,
    const int* __restrict__ src, const unsigned short* __restrict__ q,
    const unsigned short* __restrict__ kv,
    const float* __restrict__ qe, const void* __restrict__ efp,
    const int* __restrict__ flagp, float* __restrict__ av, float* __restrict__ wef) {
    int lane = threadIdx.x & 63;
    int node = (blockIdx.x * 256 + threadIdx.x) >> 6;
    if (node >= NN) return;
    int ef32 = *flagp;
    const float* efF = (const float*)efp;
    const unsigned short* efU = (const unsigned short*)efp;
    int h = lane & 3;
    int dq = lane >> 2;
    int c1 = h * 32 + dq, c2 = c1 + 16;
    float qa = b2f(q[(size_t)node * 128 + c1]);
    float qb = b2f(q[(size_t)node * 128 + c2]);
    float4 qm = *(const float4*)(qe + (size_t)node * 256 + h * 64 + 4 * dq);
    float m = -__builtin_inff(), l = 0.f, a1 = 0.f, a2 = 0.f;
    float w0 = 0.f, w1 = 0.f, w2 = 0.f, w3 = 0.f;
    int beg = rowptr[node], end = rowptr[node + 1];
    const float rs = 0.17677669529663687f;  // 1/sqrt(32)

    int nn4 = (end - beg) & ~3;
    int lim = beg + nn4;
    int i = beg;
    int ee[4], ss[4];
    if (nn4 > 0) {
#pragma unroll
        for (int u = 0; u < 4; ++u) ee[u] = perm[i + u];
#pragma unroll
        for (int u = 0; u < 4; ++u) ss[u] = src[ee[u]];
    }
    for (; i < lim; i += 4) {
        // ---- data loads for current group (3 loads per edge per lane) ----
        unsigned kua[4], kub[4];
        float f0[4], f1[4], f2[4], f3[4];
#pragma unroll
        for (int u = 0; u < 4; ++u) {
            const unsigned short* kr = kv + (size_t)ss[u] * 256;
            kua[u] = *(const unsigned*)(kr + 2 * c1);
            kub[u] = *(const unsigned*)(kr + 2 * c2);
        }
        if (ef32) {
#pragma unroll
            for (int u = 0; u < 4; ++u) {
                float4 fv = *(const float4*)(efF + (size_t)ee[u] * 64 + 4 * dq);
                f0[u] = fv.x; f1[u] = fv.y; f2[u] = fv.z; f3[u] = fv.w;
            }
        } else {
#pragma unroll
            for (int u = 0; u < 4; ++u) {
                ushort4 fu = *(const ushort4*)(efU + (size_t)ee[u] * 64 + 4 * dq);
                f0[u] = b2f(fu.x); f1[u] = b2f(fu.y); f2[u] = b2f(fu.z); f3[u] = b2f(fu.w);
            }
        }
        // ---- prefetch next group's indices (overlaps with compute below) ----
        if (i + 8 <= lim) {
#pragma unroll
            for (int u = 0; u < 4; ++u) ee[u] = perm[i + 4 + u];
#pragma unroll
            for (int u = 0; u < 4; ++u) ss[u] = src[ee[u]];
        }
        // ---- dots + cross-lane reduce (4 independent chains) ----
        float t[4];
#pragma unroll
        for (int u = 0; u < 4; ++u) {
            float ka = b2f((unsigned short)(kua[u] & 0xffffu));
            float kb = b2f((unsigned short)(kub[u] & 0xffffu));
            float tt = qa * ka + qb * kb + qm.x * f0[u] + qm.y * f1[u] +
                       qm.z * f2[u] + qm.w * f3[u];
            tt += __shfl_xor(tt, 4);
            tt += __shfl_xor(tt, 8);
            tt += __shfl_xor(tt, 16);
            tt += __shfl_xor(tt, 32);
            t[u] = tt * rs;
        }
        // ---- joint online-softmax update ----
        float mn = fmaxf(fmaxf(fmaxf(t[0], t[1]), fmaxf(t[2], t[3])), m);
        float sc = __expf(m - mn);
        float w[4];
#pragma unroll
        for (int u = 0; u < 4; ++u) w[u] = __expf(t[u] - mn);
        m = mn;
        l = l * sc + ((w[0] + w[1]) + (w[2] + w[3]));
        float sa1 = 0.f, sa2 = 0.f, sw0 = 0.f, sw1 = 0.f, sw2 = 0.f, sw3 = 0.f;
#pragma unroll
        for (int u = 0; u < 4; ++u) {
            float va = b2f((unsigned short)(kua[u] >> 16));
            float vb = b2f((unsigned short)(kub[u] >> 16));
            sa1 += w[u] * va; sa2 += w[u] * vb;
            sw0 += w[u] * f0[u]; sw1 += w[u] * f1[u];
            sw2 += w[u] * f2[u]; sw3 += w[u] * f3[u];
        }
        a1 = a1 * sc + sa1; a2 = a2 * sc + sa2;
        w0 = w0 * sc + sw0; w1 = w1 * sc + sw1;
        w2 = w2 * sc + sw2; w3 = w3 * sc + sw3;
    }
    // ---- tail (0..3 edges) ----
    for (; i < end; ++i) {
        int e = perm[i];
        int sj = src[e];
        const unsigned short* kr = kv + (size_t)sj * 256;
        unsigned kua = *(const unsigned*)(kr + 2 * c1);
        unsigned kub = *(const unsigned*)(kr + 2 * c2);
        float f0s, f1s, f2s, f3s;
        if (ef32) {
            float4 fv = *(const float4*)(efF + (size_t)e * 64 + 4 * dq);
            f0s = fv.x; f1s = fv.y; f2s = fv.z; f3s = fv.w;
        } else {
            ushort4 fu = *(const ushort4*)(efU + (size_t)e * 64 + 4 * dq);
            f0s = b2f(fu.x); f1s = b2f(fu.y); f2s = b2f(fu.z); f3s = b2f(fu.w);
        }
        float ka = b2f((unsigned short)(kua & 0xffffu));
        float kb = b2f((unsigned short)(kub & 0xffffu));
        float tt = qa * ka + qb * kb + qm.x * f0s + qm.y * f1s + qm.z * f2s + qm.w * f3s;
        tt += __shfl_xor(tt, 4);
        tt += __shfl_xor(tt, 8);
        tt += __shfl_xor(tt, 16);
        tt += __shfl_xor(tt, 32);
        float alpha = tt * rs;
        float mn = fmaxf(m, alpha);
        float sc = __expf(m - mn);
        float w = __expf(alpha - mn);
        m = mn;
        l = l * sc + w;
        float va = b2f((unsigned short)(kua >> 16));
        float vb = b2f((unsigned short)(kub >> 16));
        a1 = a1 * sc + w * va;
        a2 = a2 * sc + w * vb;
        w0 = w0 * sc + w * f0s; w1 = w1 * sc + w * f1s;
        w2 = w2 * sc + w * f2s; w3 = w3 * sc + w * f3s;
    }
    float inv = (l > 0.f) ? 1.f / l : 0.f;
    av[(size_t)node * 128 + c1] = a1 * inv;
    av[(size_t)node * 128 + c2] = a2 * inv;
    float4 wout = make_float4(w0 * inv, w1 * inv, w2 * inv, w3 * inv);
    *(float4*)(wef + (size_t)node * 256 + h * 64 + 4 * dq) = wout;
}

// ---------------- layer2 per-node flash pass (H=1, C=64), kv interleaved ----------------
__global__ void __launch_bounds__(256) node_pass2(
    const int* __restrict__ rowptr, const int* __restrict__ perm,
    const int* __restrict__ src, const unsigned short* __restrict__ q,
    const unsigned short* __restrict__ kv,
    const float* __restrict__ qe, const void* __restrict__ efp,
    const int* __restrict__ flagp, float* __restrict__ av, float* __restrict__ wef) {
    int lane = threadIdx.x & 63;
    int node = (blockIdx.x * 256 + threadIdx.x) >> 6;
    if (node >= NN) return;
    int ef32 = *flagp;
    const float* efF = (const float*)efp;
    const unsigned short* efU = (const unsigned short*)efp;
    float qa = b2f(q[(size_t)node * 64 + lane]);
    float qj = qe[(size_t)node * 64 + lane];
    float m = -__builtin_inff(), l = 0.f, a1 = 0.f, w0 = 0.f;
    int beg = rowptr[node], end = rowptr[node + 1];

    int nn4 = (end - beg) & ~3;
    int lim = beg + nn4;
    int i = beg;
    int ee[4], ss[4];
    if (nn4 > 0) {
#pragma unroll
        for (int u = 0; u < 4; ++u) ee[u] = perm[i + u];
#pragma unroll
        for (int u = 0; u < 4; ++u) ss[u] = src[ee[u]];
    }
    for (; i < lim; i += 4) {
        unsigned ku[4];
        float fj[4];
#pragma unroll
        for (int u = 0; u < 4; ++u)
            ku[u] = *(const unsigned*)(kv + (size_t)ss[u] * 128 + 2 * lane);
        if (ef32) {
#pragma unroll
            for (int u = 0; u < 4; ++u) fj[u] = efF[(size_t)ee[u] * 64 + lane];
        } else {
#pragma unroll
            for (int u = 0; u < 4; ++u) fj[u] = b2f(efU[(size_t)ee[u] * 64 + lane]);
        }
        if (i + 8 <= lim) {
#pragma unroll
            for (int u = 0; u < 4; ++u) ee[u] = perm[i + 4 + u];
#pragma unroll
            for (int u = 0; u < 4; ++u) ss[u] = src[ee[u]];
        }
        float t[4];
#pragma unroll
        for (int u = 0; u < 4; ++u) {
            float kk = b2f((unsigned short)(ku[u] & 0xffffu));
            float tt = qa * kk + qj * fj[u];
            tt += __shfl_xor(tt, 1);
            tt += __shfl_xor(tt, 2);
            tt += __shfl_xor(tt, 4);
            tt += __shfl_xor(tt, 8);
            tt += __shfl_xor(tt, 16);
            tt += __shfl_xor(tt, 32);
            t[u] = tt * 0.125f;  // 1/sqrt(64)
        }
        float mn = fmaxf(fmaxf(fmaxf(t[0], t[1]), fmaxf(t[2], t[3])), m);
        float sc = __expf(m - mn);
        float w[4];
#pragma unroll
        for (int u = 0; u < 4; ++u) w[u] = __expf(t[u] - mn);
        m = mn;
        l = l * sc + ((w[0] + w[1]) + (w[2] + w[3]));
        float sa = 0.f, sw = 0.f;
#pragma unroll
        for (int u = 0; u < 4; ++u) {
            float vv = b2f((unsigned short)(ku[u] >> 16));
            sa += w[u] * vv;
            sw += w[u] * fj[u];
        }
        a1 = a1 * sc + sa;
        w0 = w0 * sc + sw;
    }
    for (; i < end; ++i) {
        int e = perm[i];
        int sj = src[e];
        unsigned ku = *(const unsigned*)(kv + (size_t)sj * 128 + 2 * lane);
        float fj = ef32 ? efF[(size_t)e * 64 + lane] : b2f(efU[(size_t)e * 64 + lane]);
        float kk = b2f((unsigned short)(ku & 0xffffu));
        float tt = qa * kk + qj * fj;
        tt += __shfl_xor(tt, 1);
        tt += __shfl_xor(tt, 2);
        tt += __shfl_xor(tt, 4);
        tt += __shfl_xor(tt, 8);
        tt += __shfl_xor(tt, 16);
        tt += __shfl_xor(tt, 32);
        float alpha = tt * 0.125f;
        float mn = fmaxf(m, alpha);
        float sc = __expf(m - mn);
        float w = __expf(alpha - mn);
        m = mn;
        l = l * sc + w;
        float vv = b2f((unsigned short)(ku >> 16));
        a1 = a1 * sc + w * vv;
        w0 = w0 * sc + w * fj;
    }
    float inv = (l > 0.f) ? 1.f / l : 0.f;
    av[(size_t)node * 64 + lane] = a1 * inv;
    wef[(size_t)node * 64 + lane] = w0 * inv;
}

// ---------------- epilogue 1: h = relu(av + wef@We1 + s1), bf16 out ----------------
__global__ void __launch_bounds__(256) ep1_kernel(const float* __restrict__ av,
                                                  const float* __restrict__ wef,
                                                  const float* __restrict__ s1,
                                                  const unsigned short* __restrict__ We,
                                                  unsigned short* __restrict__ hout) {
    __shared__ float Ws[64 * 128];
    int tid = threadIdx.x;
    for (int i = tid; i < 64 * 128; i += 256) Ws[i] = b2f(We[i]);
    __syncthreads();
    int nl = tid >> 7;
    int c = tid & 127;
    int g = c >> 5;  // head
    for (int it = 0; it < 8; ++it) {
        int n = blockIdx.x * 16 + it * 2 + nl;
        if (n < NN) {
            const float* wr = wef + (size_t)n * 256 + g * 64;
            float acc = 0.f;
#pragma unroll
            for (int d = 0; d < 64; ++d) acc += wr[d] * Ws[d * 128 + c];
            float val = av[(size_t)n * 128 + c] + acc + s1[(size_t)n * 128 + c];
            hout[(size_t)n * 128 + c] = f2bf(fmaxf(val, 0.f));
        }
    }
}

// ---------------- epilogue 2: out = av2 + wef2@We2 + s2 (f32 output!) ----------------
__global__ void __launch_bounds__(256) ep2_kernel(const float* __restrict__ av,
                                                  const float* __restrict__ wef,
                                                  const float* __restrict__ s2,
                                                  const unsigned short* __restrict__ We,
                                                  float* __restrict__ out) {
    __shared__ float Ws[64 * 64];
    int tid = threadIdx.x;
    for (int i = tid; i < 64 * 64; i += 256) Ws[i] = b2f(We[i]);
    __syncthreads();
    int nl = tid >> 6;
    int c = tid & 63;
    for (int it = 0; it < 4; ++it) {
        int n = blockIdx.x * 16 + it * 4 + nl;
        if (n < NN) {
            const float* wr = wef + (size_t)n * 64;
            float acc = 0.f;
#pragma unroll
            for (int d = 0; d < 64; ++d) acc += wr[d] * Ws[d * 64 + c];
            float val = av[(size_t)n * 64 + c] + acc + s2[(size_t)n * 64 + c];
            out[(size_t)n * 64 + c] = val;
        }
    }
}

extern "C" void kernel_launch(void* const* d_in, const int* in_sizes, int n_in,
                              void* d_out, int out_size, void* d_ws, size_t ws_size,
                              hipStream_t stream) {
    (void)in_sizes; (void)n_in; (void)out_size; (void)ws_size;
    const int* eidx = (const int*)d_in[2];
    const int* src = eidx;
    const int* dst = eidx + EE;

    char* p = (char*)d_ws;
    auto alloc = [&](size_t bytes) {
        void* r = (void*)p;
        p += (bytes + 255) & ~(size_t)255;
        return r;
    };
    unsigned short* wts = (unsigned short*)alloc(111360 * 2);
    int* flags          = (int*)alloc(256);
    int* rowptr         = (int*)alloc((size_t)(NN + 1) * 4);
    int* cntfill        = (int*)alloc((size_t)(NN + 1) * 4);
    int* perm           = (int*)alloc((size_t)EE * 4);
    unsigned short* q1  = (unsigned short*)alloc((size_t)NN * 128 * 2);  // l2: q2
    unsigned short* kv1 = (unsigned short*)alloc((size_t)NN * 256 * 2);  // -> h | kv2
    float* qe           = (float*)alloc((size_t)NN * 256 * 4);  // -> s1 -> s2
    float* av           = (float*)alloc((size_t)NN * 128 * 4);  // l2: qe2 | av2
    float* wef          = (float*)alloc((size_t)NN * 256 * 4);  // l2: wef2

    // weight table (d_in indices 3..20, canonical bf16 in ws)
    WTab tab;
    int off = 0;
    const int wsz[18] = {16384, 128, 16384, 128, 16384, 128, 8192, 16384, 128,
                         8192, 64, 8192, 64, 8192, 64, 4096, 8192, 64};
    int offs[18];
    for (int i = 0; i < 18; ++i) {
        tab.p[i] = d_in[3 + i];
        tab.sz[i] = wsz[i];
        tab.off[i] = off;
        offs[i] = off;
        off += wsz[i];
    }
    const unsigned short* Wq1c = wts + offs[0];
    const unsigned short* bq1c = wts + offs[1];
    const unsigned short* Wk1c = wts + offs[2];
    const unsigned short* bk1c = wts + offs[3];
    const unsigned short* Wv1c = wts + offs[4];
    const unsigned short* bv1c = wts + offs[5];
    const unsigned short* We1c = wts + offs[6];
    const unsigned short* Ws1c = wts + offs[7];
    const unsigned short* bs1c = wts + offs[8];
    const unsigned short* Wq2c = wts + offs[9];
    const unsigned short* bq2c = wts + offs[10];
    const unsigned short* Wk2c = wts + offs[11];
    const unsigned short* bk2c = wts + offs[12];
    const unsigned short* Wv2c = wts + offs[13];
    const unsigned short* bv2c = wts + offs[14];
    const unsigned short* We2c = wts + offs[15];
    const unsigned short* Ws2c = wts + offs[16];
    const unsigned short* bs2c = wts + offs[17];

    hipMemsetAsync(cntfill, 0, (size_t)(NN + 1) * 4, stream);
    sniff_kernel<<<1, 64, 0, stream>>>(d_in[3], flags);
    convert_kernel<<<dim3(64, 18), 256, 0, stream>>>(tab, flags, wts);
    count_kernel<<<EE / 256, 256, 0, stream>>>(dst, cntfill);
    scan_kernel<<<1, 1024, 0, stream>>>(cntfill, rowptr);
    fill_kernel<<<EE / 256, 256, 0, stream>>>(dst, cntfill, perm);

    // ---- layer 1 ----
    int g1 = (NN + 31) / 32;
    gemm_node<unsigned short, 128, 128, 32><<<g1, 256, 0, stream>>>(d_in[0], flags, Wq1c, bq1c, q1, NN, 128, 1, 0);
    gemm_node<unsigned short, 128, 128, 32><<<g1, 256, 0, stream>>>(d_in[0], flags, Wk1c, bk1c, kv1, NN, 256, 2, 0);
    gemm_node<unsigned short, 128, 128, 32><<<g1, 256, 0, stream>>>(d_in[0], flags, Wv1c, bv1c, kv1, NN, 256, 2, 1);
    qe1_kernel<<<(NN + 7) / 8, 256, 0, stream>>>(q1, We1c, qe);
    node_pass1<<<(NN + 3) / 4, 256, 0, stream>>>(rowptr, perm, src, q1, kv1, qe,
                                                 d_in[1], flags, av, wef);
    float* s1 = qe;  // qe dead after node_pass1
    gemm_node<float, 128, 128, 32><<<g1, 256, 0, stream>>>(d_in[0], flags, Ws1c, bs1c, s1, NN, 128, 1, 0);
    unsigned short* h = kv1;  // kv1 dead after node_pass1; h = first NN*128 ushorts
    ep1_kernel<<<(NN + 15) / 16, 256, 0, stream>>>(av, wef, s1, We1c, h);

    // ---- layer 2 (reuses layer-1 buffers) ----
    unsigned short* q2 = q1;
    unsigned short* kv2 = kv1 + (size_t)NN * 128;  // second half of kv1 region
    float* s2 = qe;
    float* qe2 = av;
    float* av2 = av + (size_t)NN * 64;
    float* wef2 = wef;
    int g2 = (NN + 63) / 64;
    gemm_node<unsigned short, 128, 64, 64><<<g2, 256, 0, stream>>>(h, flags + 1, Wq2c, bq2c, q2, NN, 64, 1, 0);
    gemm_node<unsigned short, 128, 64, 64><<<g2, 256, 0, stream>>>(h, flags + 1, Wk2c, bk2c, kv2, NN, 128, 2, 0);
    gemm_node<unsigned short, 128, 64, 64><<<g2, 256, 0, stream>>>(h, flags + 1, Wv2c, bv2c, kv2, NN, 128, 2, 1);
    gemm_node<float, 128, 64, 64><<<g2, 256, 0, stream>>>(h, flags + 1, Ws2c, bs2c, s2, NN, 64, 1, 0);
    qe2_kernel<<<(NN + 3) / 4, 256, 0, stream>>>(q2, We2c, qe2);
    node_pass2<<<(NN + 3) / 4, 256, 0, stream>>>(rowptr, perm, src, q2, kv2, qe2,
                                                 d_in[1], flags, av2, wef2);
    ep2_kernel<<<(NN + 15) / 16, 256, 0, stream>>>(av2, wef2, s2, We2c,
                                                   (float*)d_out);
}